// Round 4
// baseline (240.301 us; speedup 1.0000x reference)
//
#include <hip/hip_runtime.h>
#include <hip/hip_fp16.h>

// ---------------------------------------------------------------------------
// MultiSourceGNNBlock: two independent 2-layer GAT stacks on shared input.
// R3: barrier-free attention — one wave owns (node, 128-col half, 2 heads);
// half2 gathers with SGPR-base addressing; conflict-free LDS.
// ---------------------------------------------------------------------------

#define NEG_SLOPE 0.2f

// ---------------- CSR build (both sources, one pass) ----------------

__global__ __launch_bounds__(256) void count_both_kernel(
        const int* __restrict__ ei1, int E1,
        const int* __restrict__ ei2, int E2,
        int N, int* __restrict__ cnt /* [2N] */) {
    int i = blockIdx.x * 256 + threadIdx.x;
    int tot1 = E1 + N;
    int tot2 = E2 + N;
    if (i >= tot1 + tot2) return;
    int s, j; const int* ei; int E;
    if (i < tot1) { s = 0; j = i;        ei = ei1; E = E1; }
    else          { s = 1; j = i - tot1; ei = ei2; E = E2; }
    int dst = (j < E) ? ei[E + j] : (j - E);   // row1 = dst; tail = self-loops
    atomicAdd(&cnt[s * N + dst], 1);
}

// one block per source; single-pass exclusive scan for n <= 8192
__global__ __launch_bounds__(1024) void scan_kernel(
        const int* __restrict__ cnt, int* __restrict__ rp1,
        int* __restrict__ rp2, int n) {
    __shared__ int buf[1024];
    const int* c = cnt + blockIdx.x * n;
    int* rowptr = (blockIdx.x == 0) ? rp1 : rp2;
    int tid = threadIdx.x;
    int v[8];
    int local = 0;
    int base = tid * 8;
#pragma unroll
    for (int j = 0; j < 8; j++) {
        int i = base + j;
        int x = (i < n) ? c[i] : 0;
        v[j] = local;
        local += x;
    }
    buf[tid] = local;
    __syncthreads();
    for (int off = 1; off < 1024; off <<= 1) {
        int t = (tid >= off) ? buf[tid - off] : 0;
        __syncthreads();
        buf[tid] += t;
        __syncthreads();
    }
    int prev = (tid == 0) ? 0 : buf[tid - 1];
#pragma unroll
    for (int j = 0; j < 8; j++) {
        int i = base + j;
        if (i < n) rowptr[i] = prev + v[j];
    }
    if (tid == 1023) rowptr[n] = buf[1023];
}

__global__ __launch_bounds__(256) void scatter_both_kernel(
        const int* __restrict__ ei1, int E1,
        const int* __restrict__ ei2, int E2, int N,
        const int* __restrict__ rp1, const int* __restrict__ rp2,
        int* __restrict__ cur /* [2N] */,
        int* __restrict__ csr1, int* __restrict__ csr2) {
    int i = blockIdx.x * 256 + threadIdx.x;
    int tot1 = E1 + N;
    int tot2 = E2 + N;
    if (i >= tot1 + tot2) return;
    int s, j; const int* ei; int E;
    if (i < tot1) { s = 0; j = i;        ei = ei1; E = E1; }
    else          { s = 1; j = i - tot1; ei = ei2; E = E2; }
    int src, dst;
    if (j < E) { src = ei[j]; dst = ei[E + j]; }
    else       { src = dst = j - E; }
    const int* rp = s ? rp2 : rp1;
    int* csr = s ? csr2 : csr1;
    int pos = rp[dst] + atomicAdd(&cur[s * N + dst], 1);
    csr[pos] = src;
}

// ---------------- tiled GEMM (xh = h @ W, fp16 out) + fused alpha ----------------
// Block tile 64 rows x 64 cols; blockIdx.y == head; blockIdx.z == source.

#define KT 16

struct GemmArgs {
    const float *h0, *h1, *W0, *W1, *as0, *as1, *ad0, *ad1;
    __half *xh0, *xh1;
    float *alS0, *alS1, *alD0, *alD1;
    int K, M;
};

__global__ __launch_bounds__(256) void gemm_alpha_kernel(GemmArgs g) {
    __shared__ float As[KT][64];
    __shared__ float Bs[KT][64];
    int s = blockIdx.z;
    const float* h     = s ? g.h1  : g.h0;
    const float* W     = s ? g.W1  : g.W0;
    const float* a_src = s ? g.as1 : g.as0;
    const float* a_dst = s ? g.ad1 : g.ad0;
    __half* xh = s ? g.xh1 : g.xh0;
    float* alS = s ? g.alS1 : g.alS0;
    float* alD = s ? g.alD1 : g.alD0;
    const int K = g.K;

    int tid = threadIdx.x;
    int row0 = blockIdx.x * 64;
    int head = blockIdx.y;
    int c0 = head * 64;
    int tc = tid & 15, tr = tid >> 4;

    float acc[4][4] = {};

    int arow = tid >> 2, aseg = tid & 3;   // A stage: 64 rows x (4 x float4) of KT
    int brow = tid >> 4, bseg = tid & 15;  // B stage: KT rows x (16 x float4) of 64

    const float* hA = &h[(size_t)(row0 + arow) * K + aseg * 4];
    const float* wB = &W[(size_t)brow * 256 + c0 + bseg * 4];

    for (int k0 = 0; k0 < K; k0 += KT) {
        float4 av = *(const float4*)(hA + k0);
        float4 bv = *(const float4*)(wB + (size_t)k0 * 256);
        __syncthreads();
        As[aseg * 4 + 0][arow] = av.x;
        As[aseg * 4 + 1][arow] = av.y;
        As[aseg * 4 + 2][arow] = av.z;
        As[aseg * 4 + 3][arow] = av.w;
        *(float4*)&Bs[brow][bseg * 4] = bv;
        __syncthreads();
#pragma unroll
        for (int kk = 0; kk < KT; kk++) {
            float4 a = *(const float4*)&As[kk][tr * 4];
            float4 b = *(const float4*)&Bs[kk][tc * 4];
            acc[0][0] += a.x * b.x; acc[0][1] += a.x * b.y; acc[0][2] += a.x * b.z; acc[0][3] += a.x * b.w;
            acc[1][0] += a.y * b.x; acc[1][1] += a.y * b.y; acc[1][2] += a.y * b.z; acc[1][3] += a.y * b.w;
            acc[2][0] += a.z * b.x; acc[2][1] += a.z * b.y; acc[2][2] += a.z * b.z; acc[2][3] += a.z * b.w;
            acc[3][0] += a.w * b.x; acc[3][1] += a.w * b.y; acc[3][2] += a.w * b.z; acc[3][3] += a.w * b.w;
        }
    }

    float asw0 = a_src[c0 + tc * 4 + 0], asw1 = a_src[c0 + tc * 4 + 1];
    float asw2 = a_src[c0 + tc * 4 + 2], asw3 = a_src[c0 + tc * 4 + 3];
    float adw0 = a_dst[c0 + tc * 4 + 0], adw1 = a_dst[c0 + tc * 4 + 1];
    float adw2 = a_dst[c0 + tc * 4 + 2], adw3 = a_dst[c0 + tc * 4 + 3];

#pragma unroll
    for (int i = 0; i < 4; i++) {
        int row = row0 + tr * 4 + i;
        float4 o;
        o.x = acc[i][0]; o.y = acc[i][1]; o.z = acc[i][2]; o.w = acc[i][3];
        __half2 p01 = __floats2half2_rn(o.x, o.y);
        __half2 p23 = __floats2half2_rn(o.z, o.w);
        __half2* dst2 = (__half2*)&xh[(size_t)row * 256 + c0 + tc * 4];
        dst2[0] = p01;
        dst2[1] = p23;
        float s1 = o.x * asw0 + o.y * asw1 + o.z * asw2 + o.w * asw3;
        float s2 = o.x * adw0 + o.y * adw1 + o.z * adw2 + o.w * adw3;
#pragma unroll
        for (int off = 1; off < 16; off <<= 1) {
            s1 += __shfl_xor(s1, off);
            s2 += __shfl_xor(s2, off);
        }
        if (tc == 0) {
            alS[row * 4 + head] = s1;
            alD[row * 4 + head] = s2;
        }
    }
}

// ---------------- barrier-free per-wave softmax aggregation ----------------
// Wave wv of block bid owns: node g = 2*bid + (wv>>1), column half wp = wv&1
// (cols [wp*128, wp*128+128)), heads {2*wp, 2*wp+1}. Each wave: logits +
// online softmax + half2 weighted gather — no cross-wave communication.

struct AttnArgs {
    const int *rp0, *rp1, *csr0, *csr1;
    const __half *xh0, *xh1;
    const float *alS0, *alS1, *alD0, *alD1, *b0, *b1;
    float *out0, *out1;
    int N, do_relu;
};

__global__ __launch_bounds__(256) void attn_kernel(AttnArgs a) {
    __shared__ float wLds[4][2][64];   // [wave][head-sel][edge]
    __shared__ int   sLds[4][64];      // [wave][edge]
    int tid = threadIdx.x;
    int wv = tid >> 6;
    int L  = tid & 63;
    int nd = wv >> 1;
    int wp = wv & 1;
    int g = blockIdx.x * 2 + nd;
    if (g >= 2 * a.N) return;          // whole wave exits; no barriers anywhere
    int s = (g >= a.N) ? 1 : 0;
    int dst = g - s * a.N;
    const int*    rowptr = s ? a.rp1  : a.rp0;
    const int*    csr    = s ? a.csr1 : a.csr0;
    const __half* xh     = s ? a.xh1  : a.xh0;
    const float*  alS    = s ? a.alS1 : a.alS0;
    const float*  alD    = s ? a.alD1 : a.alD0;
    const float*  bias   = s ? a.b1   : a.b0;
    float*        out    = s ? a.out1 : a.out0;

    int beg = rowptr[dst], end = rowptr[dst + 1];
    float2 ad2 = *(const float2*)&alD[dst * 4 + wp * 2];
    int hsel = L >> 5;                 // which of this wave's 2 heads my cols use

    float m0 = -1e30f, m1 = -1e30f, den0 = 0.f, den1 = 0.f;
    float accx = 0.f, accy = 0.f;
    const float* wrow = &wLds[wv][hsel][0];
    const __half* xbase = xh + (size_t)wp * 128 + (size_t)L * 2;

    for (int c = beg; c < end; c += 64) {
        int n = end - c; if (n > 64) n = 64;
        // ---- phase A: wave-parallel logits for this wave's 2 heads ----
        int src = 0;
        float e0 = -1e30f, e1 = -1e30f;
        if (L < n) {
            src = csr[c + L];
            float2 as2 = *(const float2*)&alS[src * 4 + wp * 2];
            float t0 = as2.x + ad2.x, t1 = as2.y + ad2.y;
            e0 = (t0 > 0.f) ? t0 : NEG_SLOPE * t0;
            e1 = (t1 > 0.f) ? t1 : NEG_SLOPE * t1;
        }
        sLds[wv][L] = src;
        float mx0 = e0, mx1 = e1;
#pragma unroll
        for (int off = 32; off >= 1; off >>= 1) {
            mx0 = fmaxf(mx0, __shfl_xor(mx0, off));
            mx1 = fmaxf(mx1, __shfl_xor(mx1, off));
        }
        float mn0 = fmaxf(m0, mx0), mn1 = fmaxf(m1, mx1);
        float p0 = (L < n) ? __expf(e0 - mn0) : 0.f;
        float p1 = (L < n) ? __expf(e1 - mn1) : 0.f;
        wLds[wv][0][L] = p0;
        wLds[wv][1][L] = p1;
        float ps0 = p0, ps1 = p1;
#pragma unroll
        for (int off = 32; off >= 1; off >>= 1) {
            ps0 += __shfl_xor(ps0, off);
            ps1 += __shfl_xor(ps1, off);
        }
        float sc0 = __expf(m0 - mn0), sc1 = __expf(m1 - mn1);
        den0 = den0 * sc0 + ps0;
        den1 = den1 * sc1 + ps1;
        m0 = mn0; m1 = mn1;
        float scm = hsel ? sc1 : sc0;
        accx *= scm; accy *= scm;
        // ---- phase B: weighted half2 gather, SGPR row base ----
#pragma unroll 4
        for (int i = 0; i < n; i++) {
            int si = __builtin_amdgcn_readfirstlane(sLds[wv][i]);
            float w = wrow[i];
            __half2 hv = *(const __half2*)(xbase + (size_t)si * 256);
            float2 xf = __half22float2(hv);
            accx += w * xf.x;
            accy += w * xf.y;
        }
    }
    float den = (hsel ? den1 : den0) + 1e-16f;
    int col = wp * 128 + L * 2;
    float2 b2 = *(const float2*)&bias[col];
    float2 o;
    o.x = accx / den + b2.x;
    o.y = accy / den + b2.y;
    if (a.do_relu) { o.x = fmaxf(o.x, 0.f); o.y = fmaxf(o.y, 0.f); }
    *(float2*)&out[(size_t)dst * 256 + col] = o;
}

// ---------------------------------------------------------------------------

extern "C" void kernel_launch(void* const* d_in, const int* in_sizes, int n_in,
                              void* d_out, int out_size, void* d_ws, size_t ws_size,
                              hipStream_t stream) {
    const float* h0  = (const float*)d_in[0];
    const int*   ei1 = (const int*)d_in[1];
    const int*   ei2 = (const int*)d_in[2];
    const float* W10  = (const float*)d_in[3];
    const float* as10 = (const float*)d_in[4];
    const float* ad10 = (const float*)d_in[5];
    const float* b10  = (const float*)d_in[6];
    const float* W11  = (const float*)d_in[7];
    const float* as11 = (const float*)d_in[8];
    const float* ad11 = (const float*)d_in[9];
    const float* b11  = (const float*)d_in[10];
    const float* W20  = (const float*)d_in[11];
    const float* as20 = (const float*)d_in[12];
    const float* ad20 = (const float*)d_in[13];
    const float* b20  = (const float*)d_in[14];
    const float* W21  = (const float*)d_in[15];
    const float* as21 = (const float*)d_in[16];
    const float* ad21 = (const float*)d_in[17];
    const float* b21  = (const float*)d_in[18];

    const int N  = in_sizes[0] / 64;   // 8000 nodes
    const int E1 = in_sizes[1] / 2;
    const int E2 = in_sizes[2] / 2;

    char* base = (char*)d_ws;
    size_t off = 0;
    auto carve = [&](size_t bytes) -> void* {
        void* p = base + off;
        off += (bytes + 255) & ~(size_t)255;
        return p;
    };
    int* rowptr1 = (int*)carve((size_t)(N + 1) * 4);
    int* csr1    = (int*)carve((size_t)(E1 + N) * 4);
    int* rowptr2 = (int*)carve((size_t)(N + 1) * 4);
    int* csr2    = (int*)carve((size_t)(E2 + N) * 4);
    int* cnt     = (int*)carve((size_t)2 * N * 4);
    __half* xh1  = (__half*)carve((size_t)N * 256 * 2);
    __half* xh2  = (__half*)carve((size_t)N * 256 * 2);
    float* hbuf1 = (float*)carve((size_t)N * 256 * 4);
    float* hbuf2 = (float*)carve((size_t)N * 256 * 4);
    float* alS1  = (float*)carve((size_t)N * 4 * 4);
    float* alD1  = (float*)carve((size_t)N * 4 * 4);
    float* alS2  = (float*)carve((size_t)N * 4 * 4);
    float* alD2  = (float*)carve((size_t)N * 4 * 4);
    (void)ws_size; (void)n_in;

    float* out0 = (float*)d_out;
    float* out1 = (float*)d_out + (size_t)N * 256;

    // ---- CSR build (both sources) ----
    int tot = (E1 + N) + (E2 + N);
    int cblocks = (tot + 255) / 256;
    hipMemsetAsync(cnt, 0, (size_t)2 * N * 4, stream);
    count_both_kernel<<<cblocks, 256, 0, stream>>>(ei1, E1, ei2, E2, N, cnt);
    scan_kernel<<<2, 1024, 0, stream>>>(cnt, rowptr1, rowptr2, N);
    hipMemsetAsync(cnt, 0, (size_t)2 * N * 4, stream);
    scatter_both_kernel<<<cblocks, 256, 0, stream>>>(ei1, E1, ei2, E2, N,
                                                     rowptr1, rowptr2, cnt, csr1, csr2);

    const dim3 gemmGrid((N + 63) / 64, 4, 2);
    const dim3 attnGrid(N);   // 2N nodes, 2 per block

    GemmArgs g0 = { h0, h0, W10, W20, as10, as20, ad10, ad20,
                    xh1, xh2, alS1, alS2, alD1, alD2, 64, N };
    AttnArgs a0 = { rowptr1, rowptr2, csr1, csr2, xh1, xh2,
                    alS1, alS2, alD1, alD2, b10, b20, hbuf1, hbuf2, N, 1 };
    GemmArgs g1 = { hbuf1, hbuf2, W11, W21, as11, as21, ad11, ad21,
                    xh1, xh2, alS1, alS2, alD1, alD2, 256, N };
    AttnArgs a1 = { rowptr1, rowptr2, csr1, csr2, xh1, xh2,
                    alS1, alS2, alD1, alD2, b11, b21, out0, out1, N, 0 };

    gemm_alpha_kernel<<<gemmGrid, 256, 0, stream>>>(g0);
    attn_kernel<<<attnGrid, 256, 0, stream>>>(a0);
    gemm_alpha_kernel<<<gemmGrid, 256, 0, stream>>>(g1);
    attn_kernel<<<attnGrid, 256, 0, stream>>>(a1);
}